// Round 4
// baseline (463.484 us; speedup 1.0000x reference)
//
#include <hip/hip_runtime.h>

// Unpool (conv_transpose2d, single-1 depthwise kernel), stride 2.
// in:  (8, 256, 112, 112) fp32;  out: (8, 256, 224, 224) fp32,
// out[:,:,::2,::2] = in, rest 0.
//
// Unit u (of 12,845,056): input row r=u/56, out-float4 j=u%56.
//   load  float2 @ in  + 2u            (8 B/lane, wave-dense)
//   store float4 @ out + 448r + 4j     (16 B/lane, wave-dense)
//   store zero   @ out + 448r + 224+4j (odd row, wave-dense)
// 4 units/thread, iteration-strided by 256 so every instruction stays
// lane-dense. 12,845,056 = 12,544 blocks * 1024 units exactly.
//
// NOTE: NO nontemporal loads/stores. The harness re-poisons d_out (and
// restores d_in) through the normal cache path; nt ops bypass L2 and race
// with dirty poison lines -> post-timing corruption (observed R3). Plain
// global ops are coherent with the fills.

typedef float v2f __attribute__((ext_vector_type(2)));
typedef float v4f __attribute__((ext_vector_type(4)));

__global__ __launch_bounds__(256) void unpool_dense4(
    const float* __restrict__ in, float* __restrict__ out, unsigned n)
{
    unsigned base = blockIdx.x * 1024u + threadIdx.x;

#pragma unroll
    for (int m = 0; m < 4; ++m) {
        unsigned u = base + (unsigned)m * 256u;
        if (u < n) {
            unsigned r = u / 56u;
            unsigned j = u - r * 56u;

            v2f v = *reinterpret_cast<const v2f*>(in + 2u * u);

            float* p = out + 448u * r + 4u * j;
            v4f even = {v.x, 0.0f, v.y, 0.0f};
            v4f zero = {0.0f, 0.0f, 0.0f, 0.0f};
            *reinterpret_cast<v4f*>(p)       = even;
            *reinterpret_cast<v4f*>(p + 224) = zero;
        }
    }
}

extern "C" void kernel_launch(void* const* d_in, const int* in_sizes, int n_in,
                              void* d_out, int out_size, void* d_ws, size_t ws_size,
                              hipStream_t stream)
{
    const float* x = (const float*)d_in[0];
    float* out     = (float*)d_out;

    unsigned n = (unsigned)in_sizes[0] / 2u;        // 12,845,056 units
    unsigned grid = (n + 1023u) / 1024u;            // 12,544 blocks

    unpool_dense4<<<dim3(grid), dim3(256), 0, stream>>>(x, out, n);
}